// Round 4
// baseline (432.895 us; speedup 1.0000x reference)
//
#include <hip/hip_runtime.h>
#include <math.h>

#define N_NODES 50000
#define N_EDGES 800000
#define HDIM 128
#define KD 256   // K*D

typedef float f32x4 __attribute__((ext_vector_type(4)));
typedef short s16x8 __attribute__((ext_vector_type(8)));

__device__ __forceinline__ ushort f2b(float f) {
    union { float f; unsigned u; } x; x.f = f;
    unsigned u = x.u;
    return (ushort)((u + 0x7FFF + ((u >> 16) & 1)) >> 16);   // RNE
}
__device__ __forceinline__ float b2f(ushort h) {
    union { unsigned u; float f; } x; x.u = ((unsigned)h) << 16; return x.f;
}

// ------------------------------------------------------------------ CSR build
__global__ void zero_int(int* __restrict__ p, int n) {
    int i = blockIdx.x * blockDim.x + threadIdx.x;
    if (i < n) p[i] = 0;
}

__global__ void count_deg(const int* __restrict__ dst, int* __restrict__ cnt, int e) {
    int i = blockIdx.x * blockDim.x + threadIdx.x;
    if (i < e) atomicAdd(&cnt[dst[i]], 1);
}

__global__ void calc_dinv(const int* __restrict__ cnt, float* __restrict__ dinv, int n) {
    int i = blockIdx.x * blockDim.x + threadIdx.x;
    if (i < n) dinv[i] = rsqrtf((float)(cnt[i] + 1));
}

// hierarchical scan: block-local exclusive scans + per-block totals
__global__ __launch_bounds__(1024)
void scan_blk(const int* __restrict__ cnt, int* __restrict__ offsets,
              int* __restrict__ blocksum, int n) {
    __shared__ int wsum[16];
    int tid = threadIdx.x;
    int i = blockIdx.x * 1024 + tid;
    int lane = tid & 63, wid = tid >> 6;
    int v = (i < n) ? cnt[i] : 0;
    int x = v;
    #pragma unroll
    for (int off = 1; off < 64; off <<= 1) {
        int t = __shfl_up(x, off, 64);
        if (lane >= off) x += t;
    }
    if (lane == 63) wsum[wid] = x;
    __syncthreads();
    if (wid == 0) {
        int w = (lane < 16) ? wsum[lane] : 0;
        #pragma unroll
        for (int off = 1; off < 16; off <<= 1) {
            int t = __shfl_up(w, off, 64);
            if (lane >= off) w += t;
        }
        if (lane < 16) wsum[lane] = w;
    }
    __syncthreads();
    int waveoff = (wid > 0) ? wsum[wid - 1] : 0;
    if (i < n) offsets[i] = x + waveoff - v;               // block-local exclusive
    if (tid == 1023) blocksum[blockIdx.x] = x + waveoff;   // block total
}

__global__ void scan_top(const int* __restrict__ blocksum, int* __restrict__ blockpref,
                         int* __restrict__ offsets, int nb, int n) {
    int lane = threadIdx.x;   // launched with 64 threads, nb <= 64
    int v = (lane < nb) ? blocksum[lane] : 0;
    int x = v;
    #pragma unroll
    for (int off = 1; off < 64; off <<= 1) {
        int t = __shfl_up(x, off, 64);
        if (lane >= off) x += t;
    }
    if (lane < nb) blockpref[lane] = x - v;
    if (lane == 63) offsets[n] = x;   // grand total
}

__global__ __launch_bounds__(1024)
void scan_add(int* __restrict__ offsets, int* __restrict__ cursor,
              const int* __restrict__ blockpref, int n) {
    int i = blockIdx.x * 1024 + threadIdx.x;
    if (i < n) {
        int o = offsets[i] + blockpref[blockIdx.x];
        offsets[i] = o;
        cursor[i] = o;
    }
}

__global__ void fill_csr(const int* __restrict__ src, const int* __restrict__ dst,
                         int* __restrict__ cursor, int* __restrict__ csr, int e) {
    int i = blockIdx.x * blockDim.x + threadIdx.x;
    if (i < e) {
        int d = dst[i];
        int pos = atomicAdd(&cursor[d], 1);
        csr[pos] = src[i];
    }
}

// ------------------------------------------------------------------ prep
// x (fp32) -> bf16, pre-scaled by dinv[row]
__global__ void conv_x(const float4* __restrict__ x, ushort4* __restrict__ o,
                       const float* __restrict__ dinv, int n4) {
    int i = blockIdx.x * 256 + threadIdx.x;
    if (i >= n4) return;
    int row = i >> 5;                 // 32 float4 per row
    float dv = dinv[row];
    float4 v = x[i];
    ushort4 u;
    u.x = f2b(v.x * dv); u.y = f2b(v.y * dv);
    u.z = f2b(v.z * dv); u.w = f2b(v.w * dv);
    o[i] = u;
}

// transpose + bf16 all weights: W1T[n][k], W2T[n][k], Bt3[k][n(mu|lv)][h]
__global__ void prep_w(const float* __restrict__ W1, const float* __restrict__ W2,
                       const float* __restrict__ Wmu, const float* __restrict__ Wlv,
                       ushort* __restrict__ w1t, ushort* __restrict__ w2t,
                       ushort* __restrict__ bt3) {
    int i = blockIdx.x * 256 + threadIdx.x;
    if (i < 16384) {
        int nn = i >> 7, k = i & 127;
        w1t[i] = f2b(W1[k * 128 + nn]);
    } else if (i < 32768) {
        int j = i - 16384; int nn = j >> 7, k = j & 127;
        w2t[j] = f2b(W2[k * 128 + nn]);
    } else if (i < 98304) {
        int j = i - 32768;                 // ((k*128 + n)*128 + h)
        int h = j & 127; int nk = j >> 7; int nn = nk & 127; int k = nk >> 7;
        float v = (nn < 64) ? Wmu[k * 8192 + h * 64 + nn]
                            : Wlv[k * 8192 + h * 64 + (nn - 64)];
        bt3[j] = f2b(v);
    }
}

// ------------------------------------------------------------------ propagate (bf16, column-quarter split)
// input rows PRE-SCALED by dinv[src]; out[i] = dinv[i] * (sum_nbr in[s] + in[i])
// blockIdx.y = column quarter q (outer grid dim -> dispatch keeps all blocks of
// quarter q before q+1, so the live gather slab is only 3.2 MB and stays L2-hot).
// Wave = 1 node; 16 edge slots x 4 lanes; each 4-lane group loads a 64B quarter row.
__global__ __launch_bounds__(256)
void prop_q(const ushort* __restrict__ hin, ushort* __restrict__ hout,
            const int* __restrict__ csr, const int* __restrict__ offsets,
            const float* __restrict__ dinv, int n) {
    int node = blockIdx.x * 4 + (threadIdx.x >> 6);
    if (node >= n) return;
    int lane = threadIdx.x & 63;
    int e = lane >> 2, il = lane & 3;
    int eoff = blockIdx.y * 32 + (il << 3);   // element offset within row
    int beg = offsets[node], end = offsets[node + 1];
    float acc[8] = {0.f,0.f,0.f,0.f,0.f,0.f,0.f,0.f};
    for (int base = beg; base < end; base += 64) {
        int cnt = end - base; if (cnt > 64) cnt = 64;
        int sidx = (lane < cnt) ? csr[base + lane] : 0;
        #pragma unroll 4
        for (int j = e; j < cnt; j += 16) {
            int s = __shfl(sidx, j, 64);
            s16x8 v = *(const s16x8*)(hin + (s << 7) + eoff);
            #pragma unroll
            for (int q = 0; q < 8; ++q) acc[q] += b2f((ushort)v[q]);
        }
    }
    // reduce across the 16 edge slots (lanes stride 4, same il)
    #pragma unroll
    for (int q = 0; q < 8; ++q) {
        float t = acc[q];
        t += __shfl_xor(t, 4, 64);
        t += __shfl_xor(t, 8, 64);
        t += __shfl_xor(t, 16, 64);
        t += __shfl_xor(t, 32, 64);
        acc[q] = t;
    }
    if (e == 0) {
        s16x8 sv = *(const s16x8*)(hin + (node << 7) + eoff);
        float dn = dinv[node];
        s16x8 o;
        #pragma unroll
        for (int q = 0; q < 8; ++q)
            o[q] = (short)f2b((acc[q] + b2f((ushort)sv[q])) * dn);
        *(s16x8*)(hout + (node << 7) + eoff) = o;
    }
}

// ------------------------------------------------------------------ MFMA GEMM (M x 128 @ 128 x 128)
// C = prelu(A@B + bias, alpha); Cb (bf16) = C * dinv[row] (feeds next prop)
// MODE 1 additionally writes fp32 C to Cf (hgcn output)
template<int MODE>
__global__ __launch_bounds__(256)
void gemm12(const ushort* __restrict__ A, const ushort* __restrict__ Bt,
            const float* __restrict__ bias, const float* __restrict__ alpha,
            const float* __restrict__ dinv,
            float* __restrict__ Cf, ushort* __restrict__ Cb, int nrows) {
    __shared__ char As[32768];
    __shared__ char Bs[32768];
    int tid = threadIdx.x;
    int row0 = blockIdx.x * 128;
    #pragma unroll
    for (int it = 0; it < 8; ++it) {
        int idx = tid + it * 256;
        int r = idx >> 4, cb = (idx & 15) << 4;
        int sw = cb ^ ((r & 15) << 4);
        uint4 v = make_uint4(0, 0, 0, 0);
        int row = row0 + r;
        if (row < nrows) v = *(const uint4*)((const char*)A + (size_t)row * 256 + cb);
        *(uint4*)(As + r * 256 + sw) = v;
        uint4 bv = *(const uint4*)((const char*)Bt + (size_t)idx * 16);
        *(uint4*)(Bs + r * 256 + sw) = bv;
    }
    __syncthreads();

    int w = tid >> 6, lane = tid & 63;
    int bq = lane >> 4, tr = lane & 15;
    f32x4 acc[2][8];
    #pragma unroll
    for (int mi = 0; mi < 2; ++mi)
        #pragma unroll
        for (int nj = 0; nj < 8; ++nj)
            acc[mi][nj] = (f32x4){0.f, 0.f, 0.f, 0.f};

    #pragma unroll
    for (int s = 0; s < 4; ++s) {
        int xoff = (s * 64 + bq * 16) ^ ((tr & 15) << 4);
        s16x8 af[2], bfr[8];
        #pragma unroll
        for (int mi = 0; mi < 2; ++mi)
            af[mi] = *(const s16x8*)(As + (w * 32 + mi * 16 + tr) * 256 + xoff);
        #pragma unroll
        for (int nj = 0; nj < 8; ++nj)
            bfr[nj] = *(const s16x8*)(Bs + (nj * 16 + tr) * 256 + xoff);
        #pragma unroll
        for (int mi = 0; mi < 2; ++mi)
            #pragma unroll
            for (int nj = 0; nj < 8; ++nj)
                acc[mi][nj] = __builtin_amdgcn_mfma_f32_16x16x32_bf16(af[mi], bfr[nj], acc[mi][nj], 0, 0, 0);
    }

    int g = lane >> 4, c = lane & 15;
    float aval = alpha[0];
    float bb[8];
    #pragma unroll
    for (int nj = 0; nj < 8; ++nj) bb[nj] = bias[nj * 16 + c];
    #pragma unroll
    for (int mi = 0; mi < 2; ++mi) {
        #pragma unroll
        for (int j = 0; j < 4; ++j) {
            int row = row0 + w * 32 + mi * 16 + g * 4 + j;
            if (row >= nrows) continue;
            float dv = dinv[row];
            #pragma unroll
            for (int nj = 0; nj < 8; ++nj) {
                int col = nj * 16 + c;
                float t = acc[mi][nj][j] + bb[nj];
                t = t >= 0.f ? t : aval * t;
                if (MODE) Cf[(size_t)row * 128 + col] = t;
                Cb[(size_t)row * 128 + col] = f2b(t * dv);
            }
        }
    }
}

// ------------------------------------------------------------------ mu/lv GEMM (+ fused hk, r)
// blockIdx.x = k; B tile = Bt3[k] : cols 0-63 mu, 64-127 lv
template<int FUSED>
__global__ __launch_bounds__(256)
void gemm3(const ushort* __restrict__ A, const ushort* __restrict__ Bt3,
           const float* __restrict__ bmu, const float* __restrict__ blv,
           const float* __restrict__ amu, const float* __restrict__ alv,
           const float* __restrict__ Wr, const float* __restrict__ br,
           const float* __restrict__ eps,
           float* __restrict__ out_mu, float* __restrict__ out_lv,
           float* __restrict__ out_hk, float* __restrict__ out_r, int nrows) {
    __shared__ char As[32768];
    __shared__ char Bs[32768];
    int tid = threadIdx.x;
    int k = blockIdx.x;
    int row0 = blockIdx.y * 128;
    const ushort* Bt = Bt3 + (size_t)k * 16384;
    #pragma unroll
    for (int it = 0; it < 8; ++it) {
        int idx = tid + it * 256;
        int r = idx >> 4, cb = (idx & 15) << 4;
        int sw = cb ^ ((r & 15) << 4);
        uint4 v = make_uint4(0, 0, 0, 0);
        int row = row0 + r;
        if (row < nrows) v = *(const uint4*)((const char*)A + (size_t)row * 256 + cb);
        *(uint4*)(As + r * 256 + sw) = v;
        uint4 bv = *(const uint4*)((const char*)Bt + (size_t)idx * 16);
        *(uint4*)(Bs + r * 256 + sw) = bv;
    }
    __syncthreads();

    int w = tid >> 6, lane = tid & 63;
    int bq = lane >> 4, tr = lane & 15;
    f32x4 acc[2][8];
    #pragma unroll
    for (int mi = 0; mi < 2; ++mi)
        #pragma unroll
        for (int nj = 0; nj < 8; ++nj)
            acc[mi][nj] = (f32x4){0.f, 0.f, 0.f, 0.f};

    #pragma unroll
    for (int s = 0; s < 4; ++s) {
        int xoff = (s * 64 + bq * 16) ^ ((tr & 15) << 4);
        s16x8 af[2], bfr[8];
        #pragma unroll
        for (int mi = 0; mi < 2; ++mi)
            af[mi] = *(const s16x8*)(As + (w * 32 + mi * 16 + tr) * 256 + xoff);
        #pragma unroll
        for (int nj = 0; nj < 8; ++nj)
            bfr[nj] = *(const s16x8*)(Bs + (nj * 16 + tr) * 256 + xoff);
        #pragma unroll
        for (int mi = 0; mi < 2; ++mi)
            #pragma unroll
            for (int nj = 0; nj < 8; ++nj)
                acc[mi][nj] = __builtin_amdgcn_mfma_f32_16x16x32_bf16(af[mi], bfr[nj], acc[mi][nj], 0, 0, 0);
    }

    int g = lane >> 4, c = lane & 15;
    float amuv = amu[k], alvv = alv[k];
    float brk = br[k];
    float bmv[4], blvb[4], wrv[4];
    #pragma unroll
    for (int nj = 0; nj < 4; ++nj) {
        int d = nj * 16 + c;
        bmv[nj] = bmu[k * 64 + d];
        blvb[nj] = blv[k * 64 + d];
        wrv[nj] = FUSED ? Wr[k * 64 + d] : 0.f;
    }
    #pragma unroll
    for (int mi = 0; mi < 2; ++mi) {
        float rsum[4] = {0.f, 0.f, 0.f, 0.f};
        #pragma unroll
        for (int j = 0; j < 4; ++j) {
            int row = row0 + w * 32 + mi * 16 + g * 4 + j;
            if (row >= nrows) continue;
            #pragma unroll
            for (int nj = 0; nj < 4; ++nj) {
                int d = nj * 16 + c;
                size_t oc = (size_t)row * KD + k * 64 + d;
                float m_ = acc[mi][nj][j] + bmv[nj];
                m_ = m_ >= 0.f ? m_ : amuv * m_;
                float l_ = acc[mi][nj + 4][j] + blvb[nj];
                l_ = l_ >= 0.f ? l_ : alvv * l_;
                l_ = 1.f / (1.f + __expf(-l_));
                out_mu[oc] = m_;
                out_lv[oc] = l_;
                if (FUSED) {
                    float h = fmaf(eps[oc], __expf(0.5f * l_), m_);
                    out_hk[oc] = h;
                    rsum[j] = fmaf(h, wrv[nj], rsum[j]);
                }
            }
        }
        if (FUSED) {
            #pragma unroll
            for (int j = 0; j < 4; ++j) {
                float t = rsum[j];
                t += __shfl_xor(t, 1, 64);
                t += __shfl_xor(t, 2, 64);
                t += __shfl_xor(t, 4, 64);
                t += __shfl_xor(t, 8, 64);
                if (c == 0) {
                    int row = row0 + w * 32 + mi * 16 + g * 4 + j;
                    if (row < nrows)
                        out_r[(size_t)row * 4 + k] = 1.f / (1.f + __expf(-(t + brk)));
                }
            }
        }
    }
}

// ------------------------------------------------------------------ fallback reparam + r
__global__ void hk_kernel(const float* __restrict__ mu, const float* __restrict__ lv,
                          const float* __restrict__ eps, const float* __restrict__ Wr,
                          const float* __restrict__ br, float* __restrict__ hk,
                          float* __restrict__ r, int n) {
    int gw = (blockIdx.x * blockDim.x + threadIdx.x) >> 6;
    int lane = threadIdx.x & 63;
    if (gw >= n) return;
    size_t base = (size_t)gw * KD;
    #pragma unroll
    for (int k = 0; k < 4; ++k) {
        int c = k * 64 + lane;
        float m = mu[base + c], v = lv[base + c], e = eps[base + c];
        float h = fmaf(e, __expf(0.5f * v), m);
        hk[base + c] = h;
        float t = h * Wr[k * 64 + lane];
        #pragma unroll
        for (int off = 32; off >= 1; off >>= 1) t += __shfl_xor(t, off, 64);
        if (lane == 0) r[(size_t)gw * 4 + k] = 1.f / (1.f + __expf(-(t + br[k])));
    }
}

// ------------------------------------------------------------------ launch
extern "C" void kernel_launch(void* const* d_in, const int* in_sizes, int n_in,
                              void* d_out, int out_size, void* d_ws, size_t ws_size,
                              hipStream_t stream) {
    const float* x   = (const float*)d_in[0];
    const int*   ei  = (const int*)d_in[1];
    const float* W1  = (const float*)d_in[2];
    const float* b1  = (const float*)d_in[3];
    const float* a1  = (const float*)d_in[4];
    const float* W2  = (const float*)d_in[5];
    const float* b2  = (const float*)d_in[6];
    const float* a2  = (const float*)d_in[7];
    const float* Wmu = (const float*)d_in[8];
    const float* bmu = (const float*)d_in[9];
    const float* amu = (const float*)d_in[10];
    const float* Wlv = (const float*)d_in[11];
    const float* blv = (const float*)d_in[12];
    const float* alv = (const float*)d_in[13];
    const float* Wr  = (const float*)d_in[14];
    const float* br  = (const float*)d_in[15];
    const float* eps = (const float*)d_in[16];

    float* out      = (float*)d_out;
    float* out_hgcn = out;                                  // N*128
    float* out_lv   = out + (size_t)N_NODES * HDIM;         // N*256
    float* out_mu   = out_lv + (size_t)N_NODES * KD;        // N*256
    float* out_hk   = out_mu + (size_t)N_NODES * KD;        // N*256
    float* out_r    = out_hk + (size_t)N_NODES * KD;        // N*4

    char* ws = (char*)d_ws;
    int*    cnt      = (int*)ws;                       // N ints
    int*    offsets  = (int*)(ws + 204800);            // N+1 ints
    int*    cursor   = (int*)(ws + 409600);            // N ints
    int*    csr      = (int*)(ws + 614400);            // E ints
    float*  dinv     = (float*)(ws + 3814400);         // N floats
    ushort* w1t      = (ushort*)(ws + 4014592);        // 16384 bf16
    ushort* w2t      = (ushort*)(ws + 4047360);        // 16384 bf16
    ushort* bt3      = (ushort*)(ws + 4080128);        // 65536 bf16 (ends 4211200)
    int*    blocksum = (int*)(ws + 4211200);           // 49 ints
    int*    blockpref= (int*)(ws + 4211456);           // 49 ints

    // bf16 N x 128 slots inside the hk output region (fully rewritten at the end)
    ushort* S0 = (ushort*)out_hk;
    ushort* S1 = S0 + (size_t)N_NODES * HDIM;
    ushort* S2 = S1 + (size_t)N_NODES * HDIM;
    ushort* S3 = S2 + (size_t)N_NODES * HDIM;

    const size_t P_OFF = 4211712;
    const bool fused = ws_size >= P_OFF + (size_t)N_NODES * HDIM * 2;
    ushort* P = fused ? (ushort*)(ws + P_OFF) : S1;

    const int* e_src = ei;
    const int* e_dst = ei + N_EDGES;
    const int NB = (N_NODES + 1023) / 1024;   // 49

    zero_int <<<(N_NODES + 255) / 256, 256, 0, stream>>>(cnt, N_NODES);
    count_deg<<<(N_EDGES + 255) / 256, 256, 0, stream>>>(e_dst, cnt, N_EDGES);
    calc_dinv<<<(N_NODES + 255) / 256, 256, 0, stream>>>(cnt, dinv, N_NODES);
    scan_blk <<<NB, 1024, 0, stream>>>(cnt, offsets, blocksum, N_NODES);
    scan_top <<<1, 64, 0, stream>>>(blocksum, blockpref, offsets, NB, N_NODES);
    scan_add <<<NB, 1024, 0, stream>>>(offsets, cursor, blockpref, N_NODES);
    fill_csr <<<(N_EDGES + 255) / 256, 256, 0, stream>>>(e_src, e_dst, cursor, csr, N_EDGES);

    prep_w<<<384, 256, 0, stream>>>(W1, W2, Wmu, Wlv, w1t, w2t, bt3);
    conv_x<<<(N_NODES * 32 + 255) / 256, 256, 0, stream>>>((const float4*)x, (ushort4*)S0, dinv, N_NODES * 32);

    dim3 gp(12500, 4);
    // q1 = prop(x*dinv)                       S0 -> S1
    prop_q<<<gp, 256, 0, stream>>>(S0, S1, csr, offsets, dinv, N_NODES);
    // h = prelu(q1@W1+b1); bf16 h*dinv        S1 -> S2
    gemm12<0><<<391, 256, 0, stream>>>(S1, w1t, b1, a1, dinv, nullptr, S2, N_NODES);
    // q2 = prop(h*dinv)                       S2 -> S3
    prop_q<<<gp, 256, 0, stream>>>(S2, S3, csr, offsets, dinv, N_NODES);
    // hgcn = prelu(q2@W2+b2) fp32 -> out; bf16 hgcn*dinv -> S0
    gemm12<1><<<391, 256, 0, stream>>>(S3, w2t, b2, a2, dinv, out_hgcn, S0, N_NODES);
    // p = prop(hgcn*dinv)                     S0 -> P
    prop_q<<<gp, 256, 0, stream>>>(S0, P, csr, offsets, dinv, N_NODES);

    dim3 g3(4, 391);
    if (fused) {
        gemm3<1><<<g3, 256, 0, stream>>>(P, bt3, bmu, blv, amu, alv, Wr, br, eps,
                                         out_mu, out_lv, out_hk, out_r, N_NODES);
    } else {
        gemm3<0><<<g3, 256, 0, stream>>>(P, bt3, bmu, blv, amu, alv, Wr, br, eps,
                                         out_mu, out_lv, out_hk, out_r, N_NODES);
        hk_kernel<<<12500, 256, 0, stream>>>(out_mu, out_lv, eps, Wr, br, out_hk, out_r, N_NODES);
    }
}